// Round 6
// baseline (121.617 us; speedup 1.0000x reference)
//
#include <hip/hip_runtime.h>
#include <math.h>

// Chamfer distance, fused single-sweep, minimized atomics.
// B=16, N=2048 samp, M=8192 ref, fp32.
#define BB 16
#define NN 2048
#define MM 8192

#define BLK 256
#define R 4                   // refs resident per lane
#define G (BLK * R)           // 1024 refs per block
#define QPH 32                // queries per phase (tqbuf = 32 KB)
#define PHASES 8
#define QCH (QPH * PHASES)    // 256 queries per block
#define YS (MM / G)           // 8 ref slices
#define ZS (NN / QCH)         // 8 query slices

// ws layout (16B-aligned):
//   ref4  : float4[BB*MM]   (-2x,-2y,-2z,||p||^2)  2 MB   (lane-resident side)
//   samp4 : float4[BB*NN]   (  x,  y,  z,||p||^2)  0.5 MB (streamed side)
//   ws2   : uint[BB*MM]     ref->samp mins (atomic, init +inf)   0.5 MB
//   ws1p  : float[YS][BB*NN] samp->ref partial mins (plain stores) 1 MB

__global__ void __launch_bounds__(BLK) prep_kernel(const float* __restrict__ ref,
                                                   const float* __restrict__ samp,
                                                   float4* __restrict__ ref4,
                                                   float4* __restrict__ samp4,
                                                   unsigned int* __restrict__ ws2) {
    int i = blockIdx.x * blockDim.x + threadIdx.x;
    const int PM = BB * MM, PN = BB * NN;
    if (i < PM) {
        float p1 = ref[(size_t)i * 3 + 0], p2 = ref[(size_t)i * 3 + 1], p3 = ref[(size_t)i * 3 + 2];
        float q = fmaf(p1, p1, fmaf(p2, p2, p3 * p3));
        ref4[i] = make_float4(-2.f * p1, -2.f * p2, -2.f * p3, q);
        ws2[i] = 0x7F800000u;                              // +inf
    } else if (i < PM + PN) {
        int k = i - PM;
        float p1 = samp[(size_t)k * 3 + 0], p2 = samp[(size_t)k * 3 + 1], p3 = samp[(size_t)k * 3 + 2];
        float q = fmaf(p1, p1, fmaf(p2, p2, p3 * p3));
        samp4[k] = make_float4(p1, p2, p3, q);
    }
}

// grid = (B, YS, ZS) = (16, 8, 8) = 1024 blocks; 4 blocks/CU.
// Block: 1024 refs resident in VGPRs (4/lane); streams 256 queries in 8
// phases of 32. Query-direction partials -> LDS -> per-y-slice plain store.
// Ref-direction mins -> one atomicMin per ref per block (1.05M total).
__global__ void __launch_bounds__(BLK, 4) sweep_kernel(const float4* __restrict__ ref4,
                                                       const float4* __restrict__ samp4,
                                                       unsigned int* __restrict__ ws2,
                                                       float* __restrict__ ws1p) {
    __shared__ float tqbuf[QPH * BLK];                     // [j][tid], 32 KB
    const int b = blockIdx.x;
    const int lane = threadIdx.x & 63;
    const int wv = threadIdx.x >> 6;                       // 0..3
    const int refbase = blockIdx.y * G + wv * (64 * R);

    const float4* rp = ref4 + (size_t)b * MM + refbase;
    float px[R], py[R], pz[R], pp[R], mref[R];
#pragma unroll
    for (int r = 0; r < R; ++r) {
        float4 v = rp[r * 64 + lane];                      // coalesced dwordx4
        px[r] = v.x; py[r] = v.y; pz[r] = v.z; pp[r] = v.w;
        mref[r] = INFINITY;
    }

    const int q0 = blockIdx.z * QCH;
    float* w1 = ws1p + (size_t)blockIdx.y * (BB * NN) + (size_t)b * NN + q0;

    for (int ph = 0; ph < PHASES; ++ph) {
        const float4* qt = samp4 + (size_t)b * NN + q0 + ph * QPH;

#pragma unroll 4
        for (int j = 0; j < QPH; ++j) {
            float4 q = qt[j];                              // wave-uniform broadcast
            float t[R];
#pragma unroll
            for (int r = 0; r < R; ++r) {
                float s = fmaf(px[r], q.x, pp[r]);         // pp - 2*dot
                s = fmaf(py[r], q.y, s);
                s = fmaf(pz[r], q.z, s);
                t[r] = s;
                mref[r] = fminf(mref[r], s + q.w);         // ref-direction
            }
            float tq = fminf(fminf(t[0], t[1]), fminf(t[2], t[3]));  // qw deferred
            tqbuf[j * BLK + threadIdx.x] = tq;
        }
        __syncthreads();

        // per-query block-min: wave wv handles queries wv*8 .. wv*8+7
#pragma unroll
        for (int jj = 0; jj < QPH / 4; ++jj) {
            const int j = wv * (QPH / 4) + jj;
            float4 v = ((const float4*)(tqbuf + j * BLK))[lane];
            float m = fminf(fminf(v.x, v.y), fminf(v.z, v.w));
#pragma unroll
            for (int s = 32; s > 0; s >>= 1)
                m = fminf(m, __shfl_xor(m, s));
            if (lane == 0)
                w1[ph * QPH + j] = m;                      // plain store; qw added in reduce
        }
        __syncthreads();
    }

    unsigned int* w2 = ws2 + (size_t)b * MM + refbase;
#pragma unroll
    for (int r = 0; r < R; ++r)
        atomicMin(&w2[r * 64 + lane], __float_as_uint(fmaxf(mref[r], 0.f)));
}

// Final reduce. grid = B, block = 1024.
#define BLKR 1024
__global__ void __launch_bounds__(BLKR) reduce_kernel(const float* __restrict__ ws1p,
                                                      const unsigned int* __restrict__ ws2,
                                                      const float4* __restrict__ samp4,
                                                      float* __restrict__ out) {
    const int b = blockIdx.x;
    const int tid = threadIdx.x;

    float sd1 = 0.f, sr1 = 0.f;
    for (int i = tid; i < NN; i += BLKR) {
        float m = INFINITY;
#pragma unroll
        for (int y = 0; y < YS; ++y)
            m = fminf(m, ws1p[(size_t)y * (BB * NN) + (size_t)b * NN + i]);
        float v = fmaxf(m + samp4[(size_t)b * NN + i].w, 0.f);
        sd1 += v;
        sr1 += sqrtf(v);
    }
    float sd2 = 0.f, sr2 = 0.f;
    for (int i = tid; i < MM; i += BLKR) {
        float v = __uint_as_float(ws2[(size_t)b * MM + i]);  // already >= 0
        sd2 += v;
        sr2 += sqrtf(v);
    }

    __shared__ float4 red[BLKR];
    red[tid] = make_float4(sd1, sr1, sd2, sr2);
    __syncthreads();
    for (int s = BLKR / 2; s > 0; s >>= 1) {
        if (tid < s) {
            red[tid].x += red[tid + s].x;
            red[tid].y += red[tid + s].y;
            red[tid].z += red[tid + s].z;
            red[tid].w += red[tid + s].w;
        }
        __syncthreads();
    }
    if (tid == 0) {
        float4 r = red[0];
        out[b]      = (r.y * (1.0f / NN) + r.w * (1.0f / MM)) * 0.5f;  // cd_p
        out[BB + b] = r.x * (1.0f / NN) + r.z * (1.0f / MM);           // cd_t
    }
}

extern "C" void kernel_launch(void* const* d_in, const int* in_sizes, int n_in,
                              void* d_out, int out_size, void* d_ws, size_t ws_size,
                              hipStream_t stream) {
    const float* ref  = (const float*)d_in[0];   // [B, M, 3]
    const float* samp = (const float*)d_in[1];   // [B, N, 3]
    float* out = (float*)d_out;                  // [cd_p[16], cd_t[16]]

    float4* ref4  = (float4*)d_ws;                                   // BB*MM
    float4* samp4 = ref4 + (size_t)BB * MM;                          // BB*NN
    unsigned int* ws2 = (unsigned int*)(samp4 + (size_t)BB * NN);    // BB*MM
    float* ws1p = (float*)(ws2 + (size_t)BB * MM);                   // YS*BB*NN

    const int P = BB * (MM + NN);
    prep_kernel<<<(P + BLK - 1) / BLK, BLK, 0, stream>>>(ref, samp, ref4, samp4, ws2);

    dim3 gs(BB, YS, ZS);   // (16, 8, 8) = 1024 blocks
    sweep_kernel<<<gs, BLK, 0, stream>>>(ref4, samp4, ws2, ws1p);

    reduce_kernel<<<BB, BLKR, 0, stream>>>(ws1p, ws2, samp4, out);
}